// Round 4
// baseline (947.717 us; speedup 1.0000x reference)
//
#include <hip/hip_runtime.h>
#include <hip/hip_bf16.h>
#include <math.h>

// ---------------------------------------------------------------------------
// MoE block: y = sum_topk2 w_e * FFN_e(x)  +  FFN_shared(x)
// T=4096, D=1024, H=4096, E=8, K=2.  bf16 MFMA compute.
// R4: 128x128 GEMM with 3-buffer distance-2 prefetch pipeline:
//   stage(t+2) issued ~2 K-tiles (>=1000cy) before vmcnt(16) waits tile t.
//   Counted vmcnt (never 0 in-loop), raw s_barrier (no implicit drain),
//   wrap-staging tail keeps the count uniform. 96KB LDS, 1 block/CU.
// ---------------------------------------------------------------------------

typedef unsigned short ushort_t;
typedef __attribute__((ext_vector_type(8))) __bf16 bf16x8;
typedef __attribute__((ext_vector_type(4))) float f32x4;

#define T_TOK 4096
#define DDIM  1024
#define HDIM  4096
#define NEXP  8
#define SLOT_MAX 9216            // 8192 + 8*128 pad headroom (128-aligned regions)
#define M_ALL (SLOT_MAX + T_TOK) // 13312 rows: experts then shared

// workspace layout (bytes)
#define OFF_CNT   0u             // int[8] cnt + int[8] cur
#define OFF_OFFS  64u            // int[16]
#define OFF_TIDX  256u           // int[8192]
#define OFF_TW    33024u         // float[8192]
#define OFF_SLOT  65792u         // int[8192]
#define OFF_TOK   98560u         // int[9216]
#define OFF_XALL  1048576u                        // bf16 [13312][1024] = 27,262,976
#define OFF_OUTS  OFF_XALL                        // bf16 [9216][1024] (aliases Xall)
#define OFF_WT    (OFF_XALL + 27262976u)          // bf16 [9][N][K] = 75,497,472
#define OFF_H     (OFF_WT + 75497472u)            // bf16 [13312][4096] = 109,051,904

__device__ __forceinline__ ushort_t f2b(float f) {
    __hip_bfloat16 h = __float2bfloat16(f);
    return *reinterpret_cast<ushort_t*>(&h);
}
__device__ __forceinline__ float b2f(ushort_t u) {
    __hip_bfloat16 h;
    *reinterpret_cast<ushort_t*>(&h) = u;
    return __bfloat162float(h);
}
__device__ __forceinline__ float gelu_exact(float v) {
    return 0.5f * v * (1.0f + erff(v * 0.70710678118654752f));
}

// -------------------------------- init -------------------------------------
__global__ void init_kernel(int* __restrict__ cnt, int* __restrict__ tok_of) {
    int i = blockIdx.x * 256 + threadIdx.x;
    if (i < 16) cnt[i] = 0;
    if (i < SLOT_MAX) tok_of[i] = -1;
}

// -------------------------------- gate -------------------------------------
__global__ void gate_kernel(const float* __restrict__ x, const float* __restrict__ gw,
                            int* __restrict__ tidx, float* __restrict__ tw,
                            int* __restrict__ cnt) {
    int t = blockIdx.x;
    int l = threadIdx.x;
    float acc[NEXP];
#pragma unroll
    for (int e = 0; e < NEXP; ++e) acc[e] = 0.f;
    for (int i = 0; i < DDIM / 64; ++i) {
        float xi = x[(size_t)t * DDIM + i * 64 + l];
#pragma unroll
        for (int e = 0; e < NEXP; ++e)
            acc[e] += xi * gw[e * DDIM + i * 64 + l];
    }
#pragma unroll
    for (int e = 0; e < NEXP; ++e)
        for (int off = 32; off; off >>= 1) acc[e] += __shfl_xor(acc[e], off);
    if (l == 0) {
        float m = acc[0];
#pragma unroll
        for (int e = 1; e < NEXP; ++e) m = fmaxf(m, acc[e]);
        float ex[NEXP], Z = 0.f;
#pragma unroll
        for (int e = 0; e < NEXP; ++e) { ex[e] = __expf(acc[e] - m); Z += ex[e]; }
        int b0 = 0;
#pragma unroll
        for (int e = 1; e < NEXP; ++e) if (ex[e] > ex[b0]) b0 = e;
        int b1 = (b0 == 0) ? 1 : 0;
#pragma unroll
        for (int e = 0; e < NEXP; ++e) if (e != b0 && ex[e] > ex[b1]) b1 = e;
        float inv = 1.0f / Z;
        tidx[2 * t] = b0; tidx[2 * t + 1] = b1;
        tw[2 * t] = ex[b0] * inv; tw[2 * t + 1] = ex[b1] * inv;
        atomicAdd(&cnt[b0], 1);
        atomicAdd(&cnt[b1], 1);
    }
}

// ------------------------------ offsets ------------------------------------
__global__ void offs_kernel(const int* __restrict__ cnt, int* __restrict__ offs) {
    if (threadIdx.x == 0 && blockIdx.x == 0) {
        int o = 0;
#pragma unroll
        for (int e = 0; e < NEXP; ++e) {
            offs[e] = o;
            o += (cnt[e] + 127) & ~127;
        }
        offs[NEXP] = o;
    }
}

// ------------------------------- assign ------------------------------------
// slot order within an expert is atomic-race-dependent, but the OUTPUT is
// permutation-invariant (each slot row computed independently).
__global__ void assign_kernel(const int* __restrict__ tidx, const int* __restrict__ offs,
                              int* __restrict__ cur, int* __restrict__ slot_of,
                              int* __restrict__ tok_of) {
    int i = blockIdx.x * 256 + threadIdx.x;
    if (i >= 2 * T_TOK) return;
    int e = tidx[i];
    int s = offs[e] + atomicAdd(&cur[e], 1);
    slot_of[i] = s;
    tok_of[s] = i >> 1;
}

// ------------------------------- build X -----------------------------------
__global__ void build_x(const float* __restrict__ x, const int* __restrict__ tok_of,
                        const int* __restrict__ offs, ushort_t* __restrict__ Xall) {
    int b = blockIdx.x;
    int k = threadIdx.x * 4;
    int t;
    if (b < SLOT_MAX) {
        if (b >= offs[NEXP]) return;
        t = tok_of[b];
    } else {
        t = b - SLOT_MAX;
    }
    float4 v = make_float4(0.f, 0.f, 0.f, 0.f);
    if (t >= 0) v = *(const float4*)(x + (size_t)t * DDIM + k);
    ushort_t* p = Xall + (size_t)b * DDIM + k;
    p[0] = f2b(v.x); p[1] = f2b(v.y); p[2] = f2b(v.z); p[3] = f2b(v.w);
}

// --------------------------- transpose + cvt -------------------------------
// in [K][N] fp32 -> out [N][K] bf16 ; grid (K/64, N/64, batch)
__global__ void transpose_cvt(const float* __restrict__ in, ushort_t* __restrict__ out,
                              int K, int N) {
    __shared__ float t[64][65];
    size_t zoff = (size_t)blockIdx.z * K * N;
    in += zoff; out += zoff;
    int k0 = blockIdx.x * 64, n0 = blockIdx.y * 64;
    int c = threadIdx.x & 63, r4 = threadIdx.x >> 6;
#pragma unroll
    for (int i = 0; i < 16; ++i) {
        int r = r4 + i * 4;
        t[r][c] = in[(size_t)(k0 + r) * N + n0 + c];
    }
    __syncthreads();
#pragma unroll
    for (int i = 0; i < 16; ++i) {
        int r = r4 + i * 4;
        out[(size_t)(n0 + r) * K + k0 + c] = f2b(t[c][r]);
    }
}

// --------------------- GEMM 128x128, 3-buf distance-2 ----------------------
// C[M,N] = act(A[M,K] @ Bt[e][N,K]^T + bias), rows grouped by expert
// (128-aligned), expert 8 = shared. 4 waves, BK=64, mfma 16x16x32 bf16.
// Pipeline: stage(t+2)->buf[(t+2)%3]; vmcnt(16) [tile t drained, t+1/t+2
// in flight]; s_barrier; ds_read+MFMA(buf[t%3]); s_barrier.
// Wrap-staging in the tail keeps vmcnt count uniform (staged data unread).
// Chunk-XOR LDS swizzle (0 conflicts measured) w/ pre-swizzled source.
template <bool ACT_GELU, bool FFN2>
__global__ __launch_bounds__(256) void gemm_moe(
    const ushort_t* __restrict__ A, const ushort_t* __restrict__ WtBase,
    const float* __restrict__ bExp, const float* __restrict__ bSh,
    ushort_t* __restrict__ Cb, float* __restrict__ Cf,
    const int* __restrict__ offs, int N, int K) {
    // ---- block swizzle: XCD-chunked + column-pair (L2 reuse; R3-proven) ----
    int MT = gridDim.x;
    int nwg = MT * gridDim.y;            // multiple of 8 (3328 / 832)
    int flat = blockIdx.y * MT + blockIdx.x;
    int q8 = nwg >> 3;
    int idx = (flat & 7) * q8 + (flat >> 3);
    int pairsz = MT * 2;
    int pp = idx / pairsz, rr = idx % pairsz;
    int m0 = (rr >> 1) * 128;
    int n0 = (pp * 2 + (rr & 1)) * 128;

    int e;
    if (m0 >= SLOT_MAX) {
        e = NEXP;                        // shared region
    } else {
        if (m0 >= offs[NEXP]) return;    // dead pad zone (before any barrier)
        e = 0;
        while (offs[e + 1] <= m0) e++;
    }
    const ushort_t* Bt = WtBase + (size_t)e * N * K;
    const float* bias = (e == NEXP) ? bSh : bExp + (size_t)e * N;

    __shared__ ushort_t As[3][128 * 64];   // 3-deep rotating buffers
    __shared__ ushort_t Bs[3][128 * 64];   // 96 KiB total

    int tid = threadIdx.x;
    int lane = tid & 63, wid = tid >> 6;
    int wm = wid >> 1, wn = wid & 1;
    int q = lane >> 4, lr = lane & 15;

    // staging: chunk L = it*256 + tid ; row = L>>3, stored chunk = L&7,
    // source chunk = stored ^ (row&7)  (rule #21: pre-swizzled source)
    size_t Aoff[4], Boff[4];
    int ldsOff[4];
#pragma unroll
    for (int it = 0; it < 4; ++it) {
        int row = it * 32 + (tid >> 3);
        int c = (tid & 7) ^ (row & 7);
        Aoff[it] = (size_t)(m0 + row) * K + c * 8;
        Boff[it] = (size_t)(n0 + row) * K + c * 8;
        ldsOff[it] = (it * 256 + wid * 64) * 8;   // ushort elements
    }

    int rowA[4], rowB[4];
#pragma unroll
    for (int i = 0; i < 4; ++i) {
        rowA[i] = wm * 64 + i * 16 + lr;
        rowB[i] = wn * 64 + i * 16 + lr;
    }

    f32x4 acc[4][4];
#pragma unroll
    for (int i = 0; i < 4; ++i)
#pragma unroll
        for (int j = 0; j < 4; ++j) acc[i][j] = (f32x4)(0.f);

    auto stage = [&](int kb, int buf) {   // 8 gload_lds per thread-call
#pragma unroll
        for (int it = 0; it < 4; ++it) {
            __builtin_amdgcn_global_load_lds(
                (const __attribute__((address_space(1))) void*)(A + Aoff[it] + kb),
                (__attribute__((address_space(3))) void*)(&As[buf][ldsOff[it]]), 16, 0, 0);
            __builtin_amdgcn_global_load_lds(
                (const __attribute__((address_space(1))) void*)(Bt + Boff[it] + kb),
                (__attribute__((address_space(3))) void*)(&Bs[buf][ldsOff[it]]), 16, 0, 0);
        }
    };
    auto compute = [&](int buf) {
#pragma unroll
        for (int ks = 0; ks < 2; ++ks) {
            bf16x8 af[4], bfr[4];
#pragma unroll
            for (int i = 0; i < 4; ++i) {
                int cA = (ks * 4 + q) ^ (rowA[i] & 7);
                af[i] = *(const bf16x8*)(&As[buf][rowA[i] * 64 + cA * 8]);
                int cB = (ks * 4 + q) ^ (rowB[i] & 7);
                bfr[i] = *(const bf16x8*)(&Bs[buf][rowB[i] * 64 + cB * 8]);
            }
#pragma unroll
            for (int i = 0; i < 4; ++i)
#pragma unroll
                for (int j = 0; j < 4; ++j)
                    acc[i][j] = __builtin_amdgcn_mfma_f32_16x16x32_bf16(
                        af[i], bfr[j], acc[i][j], 0, 0, 0);
        }
    };

    const int nk = K >> 6;               // 16 or 64 (>= 3)
    // prologue: two tiles in flight
    stage(0, 0);
    stage(64, 1);
    int bc = 0, bs = 2;                  // compute-buf, stage-buf
    for (int t = 0; t < nk; ++t) {
        int kn = t + 2;
        if (kn >= nk) kn -= nk;          // wrap: keeps vmcnt uniform; data unread
        stage(kn << 6, bs);
        asm volatile("s_waitcnt vmcnt(16)" ::: "memory");  // tile t drained
        __builtin_amdgcn_s_barrier();
        compute(bc);
        __builtin_amdgcn_s_barrier();
        bc = (bc == 2) ? 0 : bc + 1;
        bs = (bs == 2) ? 0 : bs + 1;
    }

    // epilogue: C/D map col=lane&15, row=(lane>>4)*4+reg
    int colb = n0 + wn * 64 + lr;
    int rowb = m0 + wm * 64 + q * 4;
#pragma unroll
    for (int j = 0; j < 4; ++j) {
        int col = colb + j * 16;
        float bz = bias[col];
#pragma unroll
        for (int i = 0; i < 4; ++i) {
            int row = rowb + i * 16;
#pragma unroll
            for (int r = 0; r < 4; ++r) {
                float v = acc[i][j][r] + bz;
                if (ACT_GELU) v = gelu_exact(v);
                if (!FFN2 || e < NEXP)
                    Cb[(size_t)(row + r) * N + col] = f2b(v);
                else
                    Cf[(size_t)(row + r - SLOT_MAX) * N + col] = v;
            }
        }
    }
}

// ------------------------------- combine -----------------------------------
__global__ void combine_kernel(float* __restrict__ out, const ushort_t* __restrict__ OutS,
                               const int* __restrict__ slot_of, const float* __restrict__ tw) {
    int t = blockIdx.x;
    int d = threadIdx.x * 4;
    int s0 = slot_of[2 * t], s1 = slot_of[2 * t + 1];
    float w0 = tw[2 * t], w1 = tw[2 * t + 1];
    float* po = out + (size_t)t * DDIM + d;
    float4 o = *(float4*)po;
    const ushort_t* p0 = OutS + (size_t)s0 * DDIM + d;
    const ushort_t* p1 = OutS + (size_t)s1 * DDIM + d;
    o.x += w0 * b2f(p0[0]) + w1 * b2f(p1[0]);
    o.y += w0 * b2f(p0[1]) + w1 * b2f(p1[1]);
    o.z += w0 * b2f(p0[2]) + w1 * b2f(p1[2]);
    o.w += w0 * b2f(p0[3]) + w1 * b2f(p1[3]);
    *(float4*)po = o;
}

// ------------------------------- launch ------------------------------------
extern "C" void kernel_launch(void* const* d_in, const int* in_sizes, int n_in,
                              void* d_out, int out_size, void* d_ws, size_t ws_size,
                              hipStream_t stream) {
    const float* x      = (const float*)d_in[0];
    const float* gw     = (const float*)d_in[1];
    const float* w_in   = (const float*)d_in[2];
    const float* b_in   = (const float*)d_in[3];
    const float* w_out  = (const float*)d_in[4];
    const float* b_out  = (const float*)d_in[5];
    const float* sw_in  = (const float*)d_in[6];
    const float* sb_in  = (const float*)d_in[7];
    const float* sw_out = (const float*)d_in[8];
    const float* sb_out = (const float*)d_in[9];
    float* out = (float*)d_out;

    char* ws = (char*)d_ws;
    int*      cnt     = (int*)(ws + OFF_CNT);      // [0..7]=cnt, [8..15]=cur
    int*      offs    = (int*)(ws + OFF_OFFS);
    int*      tidx    = (int*)(ws + OFF_TIDX);
    float*    tw      = (float*)(ws + OFF_TW);
    int*      slot_of = (int*)(ws + OFF_SLOT);
    int*      tok_of  = (int*)(ws + OFF_TOK);
    ushort_t* Xall    = (ushort_t*)(ws + OFF_XALL);
    ushort_t* OutS    = (ushort_t*)(ws + OFF_OUTS); // aliases Xall (used after GEMM1)
    ushort_t* Wt      = (ushort_t*)(ws + OFF_WT);   // [9][N][K], FFN1 then FFN2
    ushort_t* Hbuf    = (ushort_t*)(ws + OFF_H);    // bf16 [13312][4096]

    // routing
    init_kernel<<<(SLOT_MAX + 255) / 256, 256, 0, stream>>>(cnt, tok_of);
    gate_kernel<<<T_TOK, 64, 0, stream>>>(x, gw, tidx, tw, cnt);
    offs_kernel<<<1, 64, 0, stream>>>(cnt, offs);
    assign_kernel<<<(2 * T_TOK + 255) / 256, 256, 0, stream>>>(tidx, offs, cnt + 8,
                                                               slot_of, tok_of);
    build_x<<<M_ALL, 256, 0, stream>>>(x, tok_of, offs, Xall);

    // FFN1 weights: [9][4096][1024] bf16  (w_in experts + sw_in as expert 8)
    transpose_cvt<<<dim3(DDIM / 64, HDIM / 64, NEXP), 256, 0, stream>>>(w_in, Wt, DDIM, HDIM);
    transpose_cvt<<<dim3(DDIM / 64, HDIM / 64, 1), 256, 0, stream>>>(
        sw_in, Wt + (size_t)NEXP * HDIM * DDIM, DDIM, HDIM);
    // H = gelu(Xall @ W1 + b1)
    gemm_moe<true, false><<<dim3(M_ALL / 128, HDIM / 128), 256, 0, stream>>>(
        Xall, Wt, b_in, sb_in, Hbuf, nullptr, offs, HDIM, DDIM);

    // FFN2 weights: [9][1024][4096] bf16
    transpose_cvt<<<dim3(HDIM / 64, DDIM / 64, NEXP), 256, 0, stream>>>(w_out, Wt, HDIM, DDIM);
    transpose_cvt<<<dim3(HDIM / 64, DDIM / 64, 1), 256, 0, stream>>>(
        sw_out, Wt + (size_t)NEXP * HDIM * DDIM, HDIM, DDIM);
    // expert rows -> OutS (bf16); shared rows -> out (fp32, includes bias)
    gemm_moe<false, true><<<dim3(M_ALL / 128, DDIM / 128), 256, 0, stream>>>(
        Hbuf, Wt, b_out, sb_out, OutS, out, offs, DDIM, HDIM);

    // out += w0*OutS[slot0] + w1*OutS[slot1]
    combine_kernel<<<T_TOK, 256, 0, stream>>>(out, OutS, slot_of, tw);
    (void)in_sizes; (void)n_in; (void)out_size; (void)ws_size;
}

// Round 5
// 640.822 us; speedup vs baseline: 1.4789x; 1.4789x over previous
//
#include <hip/hip_runtime.h>
#include <hip/hip_bf16.h>
#include <math.h>

// ---------------------------------------------------------------------------
// MoE block: y = sum_topk2 w_e * FFN_e(x)  +  FFN_shared(x)
// T=4096, D=1024, H=4096, E=8, K=2.  bf16 MFMA compute.
// R5: R2's proven 2-phase dbuf GEMM (was at the tile-feed floor) + per-XCD
// 2-D patch swizzle so the B/A tile feed hits L2 (34.5 TB/s) instead of
// streaming from L3/HBM (~6.4 TB/s measured ceiling), + fast tanh-GELU
// epilogue. Inner loop untouched.
// ---------------------------------------------------------------------------

typedef unsigned short ushort_t;
typedef __attribute__((ext_vector_type(8))) __bf16 bf16x8;
typedef __attribute__((ext_vector_type(4))) float f32x4;

#define T_TOK 4096
#define DDIM  1024
#define HDIM  4096
#define NEXP  8
#define SLOT_MAX 9216            // 8192 + 8*128 pad headroom
#define M_ALL (SLOT_MAX + T_TOK) // 13312 rows: experts then shared

// workspace layout (bytes)
#define OFF_CNT   0u             // int[8] cnt + int[8] cur
#define OFF_OFFS  64u            // int[16]
#define OFF_TIDX  256u           // int[8192]
#define OFF_TW    33024u         // float[8192]
#define OFF_SLOT  65792u         // int[8192]
#define OFF_TOK   98560u         // int[9216]
#define OFF_XALL  1048576u                        // bf16 [13312][1024] = 27,262,976
#define OFF_OUTS  OFF_XALL                        // bf16 [9216][1024] (aliases Xall)
#define OFF_WT    (OFF_XALL + 27262976u)          // bf16 [9][N][K] = 75,497,472
#define OFF_H     (OFF_WT + 75497472u)            // bf16 [13312][4096] = 109,051,904

__device__ __forceinline__ ushort_t f2b(float f) {
    __hip_bfloat16 h = __float2bfloat16(f);
    return *reinterpret_cast<ushort_t*>(&h);
}
__device__ __forceinline__ float b2f(ushort_t u) {
    __hip_bfloat16 h;
    *reinterpret_cast<ushort_t*>(&h) = u;
    return __bfloat162float(h);
}
// tanh-form GELU (max |dev| from exact erf-GELU ~3e-3; bf16-safe here)
__device__ __forceinline__ float gelu_fast(float v) {
    float u = 0.7978845608f * v * (1.0f + 0.044715f * v * v);
    float t = 1.0f - 2.0f / (__expf(2.0f * u) + 1.0f);
    return 0.5f * v * (1.0f + t);
}

// -------------------------------- init -------------------------------------
__global__ void init_kernel(int* __restrict__ cnt, int* __restrict__ tok_of) {
    int i = blockIdx.x * 256 + threadIdx.x;
    if (i < 16) cnt[i] = 0;
    if (i < SLOT_MAX) tok_of[i] = -1;
}

// -------------------------------- gate -------------------------------------
__global__ void gate_kernel(const float* __restrict__ x, const float* __restrict__ gw,
                            int* __restrict__ tidx, float* __restrict__ tw,
                            int* __restrict__ cnt) {
    int t = blockIdx.x;
    int l = threadIdx.x;
    float acc[NEXP];
#pragma unroll
    for (int e = 0; e < NEXP; ++e) acc[e] = 0.f;
    for (int i = 0; i < DDIM / 64; ++i) {
        float xi = x[(size_t)t * DDIM + i * 64 + l];
#pragma unroll
        for (int e = 0; e < NEXP; ++e)
            acc[e] += xi * gw[e * DDIM + i * 64 + l];
    }
#pragma unroll
    for (int e = 0; e < NEXP; ++e)
        for (int off = 32; off; off >>= 1) acc[e] += __shfl_xor(acc[e], off);
    if (l == 0) {
        float m = acc[0];
#pragma unroll
        for (int e = 1; e < NEXP; ++e) m = fmaxf(m, acc[e]);
        float ex[NEXP], Z = 0.f;
#pragma unroll
        for (int e = 0; e < NEXP; ++e) { ex[e] = __expf(acc[e] - m); Z += ex[e]; }
        int b0 = 0;
#pragma unroll
        for (int e = 1; e < NEXP; ++e) if (ex[e] > ex[b0]) b0 = e;
        int b1 = (b0 == 0) ? 1 : 0;
#pragma unroll
        for (int e = 0; e < NEXP; ++e) if (e != b0 && ex[e] > ex[b1]) b1 = e;
        float inv = 1.0f / Z;
        tidx[2 * t] = b0; tidx[2 * t + 1] = b1;
        tw[2 * t] = ex[b0] * inv; tw[2 * t + 1] = ex[b1] * inv;
        atomicAdd(&cnt[b0], 1);
        atomicAdd(&cnt[b1], 1);
    }
}

// ------------------------------ offsets ------------------------------------
__global__ void offs_kernel(const int* __restrict__ cnt, int* __restrict__ offs) {
    if (threadIdx.x == 0 && blockIdx.x == 0) {
        int o = 0;
#pragma unroll
        for (int e = 0; e < NEXP; ++e) {
            offs[e] = o;
            o += (cnt[e] + 127) & ~127;
        }
        offs[NEXP] = o;
    }
}

// ------------------------------- assign ------------------------------------
// slot order within an expert is atomic-race-dependent, but the OUTPUT is
// permutation-invariant (each slot row computed independently).
__global__ void assign_kernel(const int* __restrict__ tidx, const int* __restrict__ offs,
                              int* __restrict__ cur, int* __restrict__ slot_of,
                              int* __restrict__ tok_of) {
    int i = blockIdx.x * 256 + threadIdx.x;
    if (i >= 2 * T_TOK) return;
    int e = tidx[i];
    int s = offs[e] + atomicAdd(&cur[e], 1);
    slot_of[i] = s;
    tok_of[s] = i >> 1;
}

// ------------------------------- build X -----------------------------------
__global__ void build_x(const float* __restrict__ x, const int* __restrict__ tok_of,
                        const int* __restrict__ offs, ushort_t* __restrict__ Xall) {
    int b = blockIdx.x;
    int k = threadIdx.x * 4;
    int t;
    if (b < SLOT_MAX) {
        if (b >= offs[NEXP]) return;
        t = tok_of[b];
    } else {
        t = b - SLOT_MAX;
    }
    float4 v = make_float4(0.f, 0.f, 0.f, 0.f);
    if (t >= 0) v = *(const float4*)(x + (size_t)t * DDIM + k);
    ushort_t* p = Xall + (size_t)b * DDIM + k;
    p[0] = f2b(v.x); p[1] = f2b(v.y); p[2] = f2b(v.z); p[3] = f2b(v.w);
}

// --------------------------- transpose + cvt -------------------------------
// in [K][N] fp32 -> out [N][K] bf16 ; grid (K/64, N/64, batch)
__global__ void transpose_cvt(const float* __restrict__ in, ushort_t* __restrict__ out,
                              int K, int N) {
    __shared__ float t[64][65];
    size_t zoff = (size_t)blockIdx.z * K * N;
    in += zoff; out += zoff;
    int k0 = blockIdx.x * 64, n0 = blockIdx.y * 64;
    int c = threadIdx.x & 63, r4 = threadIdx.x >> 6;
#pragma unroll
    for (int i = 0; i < 16; ++i) {
        int r = r4 + i * 4;
        t[r][c] = in[(size_t)(k0 + r) * N + n0 + c];
    }
    __syncthreads();
#pragma unroll
    for (int i = 0; i < 16; ++i) {
        int r = r4 + i * 4;
        out[(size_t)(n0 + r) * K + k0 + c] = f2b(t[c][r]);
    }
}

// ------------------------------ GEMM (bt) ----------------------------------
// C[M,N] = act(A[M,K] @ Bt[e][N,K]^T + bias), rows grouped by expert
// (128-aligned), expert 8 = shared. 128x128 tile, BK=64, 4 waves,
// mfma_f32_16x16x32_bf16, XOR-swizzled LDS, 2-phase dbuf prefetch (R2 loop,
// measured at the tile-feed floor).
// R5: per-XCD 2-D patch swizzle. XCD = flat%8 owns a (NM/4 m x NN/2 n)
// patch traversed n-minor, so the ~64 concurrently-resident blocks of an
// XCD share a ~4MB B-panel window + ~1MB A window -> tile feed served from
// that XCD's L2 instead of streaming 1.6GB from L3/HBM.
template <bool ACT_GELU, bool FFN2>
__global__ __launch_bounds__(256) void gemm_moe(
    const ushort_t* __restrict__ A, const ushort_t* __restrict__ WtBase,
    const float* __restrict__ bExp, const float* __restrict__ bSh,
    ushort_t* __restrict__ Cb, float* __restrict__ Cf,
    const int* __restrict__ offs, int N, int K) {
    // ---- per-XCD patch swizzle (bijective; NM%4==0, NN%2==0) ----
    int NMt = gridDim.x, NNt = gridDim.y;
    int flat = blockIdx.y * NMt + blockIdx.x;
    int xcd = flat & 7, rank = flat >> 3;
    int PM = NMt >> 2;                    // patch rows   (26)
    int PN = NNt >> 1;                    // patch cols   (16 or 4)
    int pm = xcd >> 1, pn = xcd & 1;      // 4 x 2 patch grid
    int mi = pm * PM + rank / PN;
    int ni = pn * PN + rank % PN;
    int m0 = mi * 128, n0 = ni * 128;

    int e;
    if (m0 >= SLOT_MAX) {
        e = NEXP;                        // shared region
    } else {
        if (m0 >= offs[NEXP]) return;    // dead pad zone (before any barrier)
        e = 0;
        while (offs[e + 1] <= m0) e++;
    }
    const ushort_t* Bt = WtBase + (size_t)e * N * K;
    const float* bias = (e == NEXP) ? bSh : bExp + (size_t)e * N;

    __shared__ ushort_t As[2][128 * 64];
    __shared__ ushort_t Bs[2][128 * 64];

    int tid = threadIdx.x;
    int lane = tid & 63, wid = tid >> 6;
    int wm = wid >> 1, wn = wid & 1;
    int q = lane >> 4, lr = lane & 15;

    // staging: chunk L = it*256 + tid ; row = L>>3, stored chunk = L&7,
    // source chunk = stored ^ (row&7)  (rule #21: pre-swizzled source)
    size_t Aoff[4], Boff[4];
    int ldsOff[4];
#pragma unroll
    for (int it = 0; it < 4; ++it) {
        int row = it * 32 + (tid >> 3);
        int c = (tid & 7) ^ (row & 7);
        Aoff[it] = (size_t)(m0 + row) * K + c * 8;
        Boff[it] = (size_t)(n0 + row) * K + c * 8;
        ldsOff[it] = (it * 256 + wid * 64) * 8;   // ushort elements
    }

    int rowA[4], rowB[4];
#pragma unroll
    for (int i = 0; i < 4; ++i) {
        rowA[i] = wm * 64 + i * 16 + lr;
        rowB[i] = wn * 64 + i * 16 + lr;
    }

    f32x4 acc[4][4];
#pragma unroll
    for (int i = 0; i < 4; ++i)
#pragma unroll
        for (int j = 0; j < 4; ++j) acc[i][j] = (f32x4)(0.f);

    auto stage = [&](int kb, int buf) {
#pragma unroll
        for (int it = 0; it < 4; ++it) {
            __builtin_amdgcn_global_load_lds(
                (const __attribute__((address_space(1))) void*)(A + Aoff[it] + kb),
                (__attribute__((address_space(3))) void*)(&As[buf][ldsOff[it]]), 16, 0, 0);
            __builtin_amdgcn_global_load_lds(
                (const __attribute__((address_space(1))) void*)(Bt + Boff[it] + kb),
                (__attribute__((address_space(3))) void*)(&Bs[buf][ldsOff[it]]), 16, 0, 0);
        }
    };
    auto compute = [&](int buf) {
#pragma unroll
        for (int ks = 0; ks < 2; ++ks) {
            bf16x8 af[4], bfr[4];
#pragma unroll
            for (int i = 0; i < 4; ++i) {
                int cA = (ks * 4 + q) ^ (rowA[i] & 7);
                af[i] = *(const bf16x8*)(&As[buf][rowA[i] * 64 + cA * 8]);
                int cB = (ks * 4 + q) ^ (rowB[i] & 7);
                bfr[i] = *(const bf16x8*)(&Bs[buf][rowB[i] * 64 + cB * 8]);
            }
#pragma unroll
            for (int i = 0; i < 4; ++i)
#pragma unroll
                for (int j = 0; j < 4; ++j)
                    acc[i][j] = __builtin_amdgcn_mfma_f32_16x16x32_bf16(
                        af[i], bfr[j], acc[i][j], 0, 0, 0);
        }
    };

    const int nk = K >> 6;
    stage(0, 0);
    __syncthreads();
    int cur = 0;
    for (int t = 0; t < nk; ++t) {
        if (t + 1 < nk) stage((t + 1) << 6, cur ^ 1);
        compute(cur);
        __syncthreads();
        cur ^= 1;
    }

    // epilogue: C/D map col=lane&15, row=(lane>>4)*4+reg
    int colb = n0 + wn * 64 + lr;
    int rowb = m0 + wm * 64 + q * 4;
#pragma unroll
    for (int j = 0; j < 4; ++j) {
        int col = colb + j * 16;
        float bz = bias[col];
#pragma unroll
        for (int i = 0; i < 4; ++i) {
            int row = rowb + i * 16;
#pragma unroll
            for (int r = 0; r < 4; ++r) {
                float v = acc[i][j][r] + bz;
                if (ACT_GELU) v = gelu_fast(v);
                if (!FFN2 || e < NEXP)
                    Cb[(size_t)(row + r) * N + col] = f2b(v);
                else
                    Cf[(size_t)(row + r - SLOT_MAX) * N + col] = v;
            }
        }
    }
}

// ------------------------------- combine -----------------------------------
__global__ void combine_kernel(float* __restrict__ out, const ushort_t* __restrict__ OutS,
                               const int* __restrict__ slot_of, const float* __restrict__ tw) {
    int t = blockIdx.x;
    int d = threadIdx.x * 4;
    int s0 = slot_of[2 * t], s1 = slot_of[2 * t + 1];
    float w0 = tw[2 * t], w1 = tw[2 * t + 1];
    float* po = out + (size_t)t * DDIM + d;
    float4 o = *(float4*)po;
    const ushort_t* p0 = OutS + (size_t)s0 * DDIM + d;
    const ushort_t* p1 = OutS + (size_t)s1 * DDIM + d;
    o.x += w0 * b2f(p0[0]) + w1 * b2f(p1[0]);
    o.y += w0 * b2f(p0[1]) + w1 * b2f(p1[1]);
    o.z += w0 * b2f(p0[2]) + w1 * b2f(p1[2]);
    o.w += w0 * b2f(p0[3]) + w1 * b2f(p1[3]);
    *(float4*)po = o;
}

// ------------------------------- launch ------------------------------------
extern "C" void kernel_launch(void* const* d_in, const int* in_sizes, int n_in,
                              void* d_out, int out_size, void* d_ws, size_t ws_size,
                              hipStream_t stream) {
    const float* x      = (const float*)d_in[0];
    const float* gw     = (const float*)d_in[1];
    const float* w_in   = (const float*)d_in[2];
    const float* b_in   = (const float*)d_in[3];
    const float* w_out  = (const float*)d_in[4];
    const float* b_out  = (const float*)d_in[5];
    const float* sw_in  = (const float*)d_in[6];
    const float* sb_in  = (const float*)d_in[7];
    const float* sw_out = (const float*)d_in[8];
    const float* sb_out = (const float*)d_in[9];
    float* out = (float*)d_out;

    char* ws = (char*)d_ws;
    int*      cnt     = (int*)(ws + OFF_CNT);      // [0..7]=cnt, [8..15]=cur
    int*      offs    = (int*)(ws + OFF_OFFS);
    int*      tidx    = (int*)(ws + OFF_TIDX);
    float*    tw      = (float*)(ws + OFF_TW);
    int*      slot_of = (int*)(ws + OFF_SLOT);
    int*      tok_of  = (int*)(ws + OFF_TOK);
    ushort_t* Xall    = (ushort_t*)(ws + OFF_XALL);
    ushort_t* OutS    = (ushort_t*)(ws + OFF_OUTS); // aliases Xall (used after GEMM1)
    ushort_t* Wt      = (ushort_t*)(ws + OFF_WT);   // [9][N][K], FFN1 then FFN2
    ushort_t* Hbuf    = (ushort_t*)(ws + OFF_H);    // bf16 [13312][4096]

    // routing
    init_kernel<<<(SLOT_MAX + 255) / 256, 256, 0, stream>>>(cnt, tok_of);
    gate_kernel<<<T_TOK, 64, 0, stream>>>(x, gw, tidx, tw, cnt);
    offs_kernel<<<1, 64, 0, stream>>>(cnt, offs);
    assign_kernel<<<(2 * T_TOK + 255) / 256, 256, 0, stream>>>(tidx, offs, cnt + 8,
                                                               slot_of, tok_of);
    build_x<<<M_ALL, 256, 0, stream>>>(x, tok_of, offs, Xall);

    // FFN1 weights: [9][4096][1024] bf16  (w_in experts + sw_in as expert 8)
    transpose_cvt<<<dim3(DDIM / 64, HDIM / 64, NEXP), 256, 0, stream>>>(w_in, Wt, DDIM, HDIM);
    transpose_cvt<<<dim3(DDIM / 64, HDIM / 64, 1), 256, 0, stream>>>(
        sw_in, Wt + (size_t)NEXP * HDIM * DDIM, DDIM, HDIM);
    // H = gelu(Xall @ W1 + b1)
    gemm_moe<true, false><<<dim3(M_ALL / 128, HDIM / 128), 256, 0, stream>>>(
        Xall, Wt, b_in, sb_in, Hbuf, nullptr, offs, HDIM, DDIM);

    // FFN2 weights: [9][1024][4096] bf16
    transpose_cvt<<<dim3(HDIM / 64, DDIM / 64, NEXP), 256, 0, stream>>>(w_out, Wt, HDIM, DDIM);
    transpose_cvt<<<dim3(HDIM / 64, DDIM / 64, 1), 256, 0, stream>>>(
        sw_out, Wt + (size_t)NEXP * HDIM * DDIM, HDIM, DDIM);
    // expert rows -> OutS (bf16); shared rows -> out (fp32, includes bias)
    gemm_moe<false, true><<<dim3(M_ALL / 128, DDIM / 128), 256, 0, stream>>>(
        Hbuf, Wt, b_out, sb_out, OutS, out, offs, DDIM, HDIM);

    // out += w0*OutS[slot0] + w1*OutS[slot1]
    combine_kernel<<<T_TOK, 256, 0, stream>>>(out, OutS, slot_of, tw);
    (void)in_sizes; (void)n_in; (void)out_size; (void)ws_size;
}

// Round 6
// 607.413 us; speedup vs baseline: 1.5603x; 1.0550x over previous
//
#include <hip/hip_runtime.h>
#include <hip/hip_bf16.h>
#include <math.h>

// ---------------------------------------------------------------------------
// MoE block: y = sum_topk2 w_e * FFN_e(x)  +  FFN_shared(x)
// T=4096, D=1024, H=4096, E=8, K=2.  bf16 MFMA compute.
// R6: same R5 GEMM (2-phase dbuf, XOR-swizzled LDS, per-XCD patch swizzle)
// but repartitioned to 8 waves/block (512 thr, wave-tile 64x32): 16 waves/CU
// = 4 waves/SIMD to hide the per-K-tile load latency with TLP.
// ---------------------------------------------------------------------------

typedef unsigned short ushort_t;
typedef __attribute__((ext_vector_type(8))) __bf16 bf16x8;
typedef __attribute__((ext_vector_type(4))) float f32x4;

#define T_TOK 4096
#define DDIM  1024
#define HDIM  4096
#define NEXP  8
#define SLOT_MAX 9216            // 8192 + 8*128 pad headroom
#define M_ALL (SLOT_MAX + T_TOK) // 13312 rows: experts then shared

// workspace layout (bytes)
#define OFF_CNT   0u             // int[8] cnt + int[8] cur
#define OFF_OFFS  64u            // int[16]
#define OFF_TIDX  256u           // int[8192]
#define OFF_TW    33024u         // float[8192]
#define OFF_SLOT  65792u         // int[8192]
#define OFF_TOK   98560u         // int[9216]
#define OFF_XALL  1048576u                        // bf16 [13312][1024] = 27,262,976
#define OFF_OUTS  OFF_XALL                        // bf16 [9216][1024] (aliases Xall)
#define OFF_WT    (OFF_XALL + 27262976u)          // bf16 [9][N][K] = 75,497,472
#define OFF_H     (OFF_WT + 75497472u)            // bf16 [13312][4096] = 109,051,904

__device__ __forceinline__ ushort_t f2b(float f) {
    __hip_bfloat16 h = __float2bfloat16(f);
    return *reinterpret_cast<ushort_t*>(&h);
}
__device__ __forceinline__ float b2f(ushort_t u) {
    __hip_bfloat16 h;
    *reinterpret_cast<ushort_t*>(&h) = u;
    return __bfloat162float(h);
}
// tanh-form GELU (max |dev| from exact erf-GELU ~3e-3; bf16-safe here)
__device__ __forceinline__ float gelu_fast(float v) {
    float u = 0.7978845608f * v * (1.0f + 0.044715f * v * v);
    float t = 1.0f - 2.0f / (__expf(2.0f * u) + 1.0f);
    return 0.5f * v * (1.0f + t);
}

// -------------------------------- init -------------------------------------
__global__ void init_kernel(int* __restrict__ cnt, int* __restrict__ tok_of) {
    int i = blockIdx.x * 256 + threadIdx.x;
    if (i < 16) cnt[i] = 0;
    if (i < SLOT_MAX) tok_of[i] = -1;
}

// -------------------------------- gate -------------------------------------
__global__ void gate_kernel(const float* __restrict__ x, const float* __restrict__ gw,
                            int* __restrict__ tidx, float* __restrict__ tw,
                            int* __restrict__ cnt) {
    int t = blockIdx.x;
    int l = threadIdx.x;
    float acc[NEXP];
#pragma unroll
    for (int e = 0; e < NEXP; ++e) acc[e] = 0.f;
    for (int i = 0; i < DDIM / 64; ++i) {
        float xi = x[(size_t)t * DDIM + i * 64 + l];
#pragma unroll
        for (int e = 0; e < NEXP; ++e)
            acc[e] += xi * gw[e * DDIM + i * 64 + l];
    }
#pragma unroll
    for (int e = 0; e < NEXP; ++e)
        for (int off = 32; off; off >>= 1) acc[e] += __shfl_xor(acc[e], off);
    if (l == 0) {
        float m = acc[0];
#pragma unroll
        for (int e = 1; e < NEXP; ++e) m = fmaxf(m, acc[e]);
        float ex[NEXP], Z = 0.f;
#pragma unroll
        for (int e = 0; e < NEXP; ++e) { ex[e] = __expf(acc[e] - m); Z += ex[e]; }
        int b0 = 0;
#pragma unroll
        for (int e = 1; e < NEXP; ++e) if (ex[e] > ex[b0]) b0 = e;
        int b1 = (b0 == 0) ? 1 : 0;
#pragma unroll
        for (int e = 0; e < NEXP; ++e) if (e != b0 && ex[e] > ex[b1]) b1 = e;
        float inv = 1.0f / Z;
        tidx[2 * t] = b0; tidx[2 * t + 1] = b1;
        tw[2 * t] = ex[b0] * inv; tw[2 * t + 1] = ex[b1] * inv;
        atomicAdd(&cnt[b0], 1);
        atomicAdd(&cnt[b1], 1);
    }
}

// ------------------------------ offsets ------------------------------------
__global__ void offs_kernel(const int* __restrict__ cnt, int* __restrict__ offs) {
    if (threadIdx.x == 0 && blockIdx.x == 0) {
        int o = 0;
#pragma unroll
        for (int e = 0; e < NEXP; ++e) {
            offs[e] = o;
            o += (cnt[e] + 127) & ~127;
        }
        offs[NEXP] = o;
    }
}

// ------------------------------- assign ------------------------------------
// slot order within an expert is atomic-race-dependent, but the OUTPUT is
// permutation-invariant (each slot row computed independently).
__global__ void assign_kernel(const int* __restrict__ tidx, const int* __restrict__ offs,
                              int* __restrict__ cur, int* __restrict__ slot_of,
                              int* __restrict__ tok_of) {
    int i = blockIdx.x * 256 + threadIdx.x;
    if (i >= 2 * T_TOK) return;
    int e = tidx[i];
    int s = offs[e] + atomicAdd(&cur[e], 1);
    slot_of[i] = s;
    tok_of[s] = i >> 1;
}

// ------------------------------- build X -----------------------------------
__global__ void build_x(const float* __restrict__ x, const int* __restrict__ tok_of,
                        const int* __restrict__ offs, ushort_t* __restrict__ Xall) {
    int b = blockIdx.x;
    int k = threadIdx.x * 4;
    int t;
    if (b < SLOT_MAX) {
        if (b >= offs[NEXP]) return;
        t = tok_of[b];
    } else {
        t = b - SLOT_MAX;
    }
    float4 v = make_float4(0.f, 0.f, 0.f, 0.f);
    if (t >= 0) v = *(const float4*)(x + (size_t)t * DDIM + k);
    ushort_t* p = Xall + (size_t)b * DDIM + k;
    p[0] = f2b(v.x); p[1] = f2b(v.y); p[2] = f2b(v.z); p[3] = f2b(v.w);
}

// --------------------------- transpose + cvt -------------------------------
// in [K][N] fp32 -> out [N][K] bf16 ; grid (K/64, N/64, batch)
__global__ void transpose_cvt(const float* __restrict__ in, ushort_t* __restrict__ out,
                              int K, int N) {
    __shared__ float t[64][65];
    size_t zoff = (size_t)blockIdx.z * K * N;
    in += zoff; out += zoff;
    int k0 = blockIdx.x * 64, n0 = blockIdx.y * 64;
    int c = threadIdx.x & 63, r4 = threadIdx.x >> 6;
#pragma unroll
    for (int i = 0; i < 16; ++i) {
        int r = r4 + i * 4;
        t[r][c] = in[(size_t)(k0 + r) * N + n0 + c];
    }
    __syncthreads();
#pragma unroll
    for (int i = 0; i < 16; ++i) {
        int r = r4 + i * 4;
        out[(size_t)(n0 + r) * K + k0 + c] = f2b(t[c][r]);
    }
}

// ------------------------------ GEMM (bt) ----------------------------------
// C[M,N] = act(A[M,K] @ Bt[e][N,K]^T + bias), rows grouped by expert
// (128-aligned), expert 8 = shared. 128x128 tile, BK=64, mfma 16x16x32 bf16,
// XOR-swizzled LDS, 2-phase dbuf prefetch, per-XCD patch swizzle (R5).
// R6: 8 waves (512 thr), wave-tile 64x32 (acc[4][2]) -> 16 waves/CU
// (4 waves/SIMD) at 2 blocks/CU, to hide the per-K-tile staging latency.
template <bool ACT_GELU, bool FFN2>
__global__ __launch_bounds__(512, 4) void gemm_moe(
    const ushort_t* __restrict__ A, const ushort_t* __restrict__ WtBase,
    const float* __restrict__ bExp, const float* __restrict__ bSh,
    ushort_t* __restrict__ Cb, float* __restrict__ Cf,
    const int* __restrict__ offs, int N, int K) {
    // ---- per-XCD patch swizzle (bijective; NM%4==0, NN%2==0) ----
    int NMt = gridDim.x, NNt = gridDim.y;
    int flat = blockIdx.y * NMt + blockIdx.x;
    int xcd = flat & 7, rank = flat >> 3;
    int PM = NMt >> 2;                    // patch rows
    int PN = NNt >> 1;                    // patch cols
    int pm = xcd >> 1, pn = xcd & 1;      // 4 x 2 patch grid
    int mi = pm * PM + rank / PN;
    int ni = pn * PN + rank % PN;
    int m0 = mi * 128, n0 = ni * 128;

    int e;
    if (m0 >= SLOT_MAX) {
        e = NEXP;                        // shared region
    } else {
        if (m0 >= offs[NEXP]) return;    // dead pad zone (before any barrier)
        e = 0;
        while (offs[e + 1] <= m0) e++;
    }
    const ushort_t* Bt = WtBase + (size_t)e * N * K;
    const float* bias = (e == NEXP) ? bSh : bExp + (size_t)e * N;

    __shared__ ushort_t As[2][128 * 64];
    __shared__ ushort_t Bs[2][128 * 64];

    int tid = threadIdx.x;
    int lane = tid & 63, wid = tid >> 6;   // 8 waves
    int wm = wid >> 2, wn = wid & 3;       // 2 x 4 wave grid
    int q = lane >> 4, lr = lane & 15;

    // staging: chunk L = it*512 + tid ; row = L>>3, stored chunk = L&7,
    // source chunk = stored ^ (row&7)  (rule #21: pre-swizzled source)
    size_t Aoff[2], Boff[2];
    int ldsOff[2];
#pragma unroll
    for (int it = 0; it < 2; ++it) {
        int L = it * 512 + tid;
        int row = L >> 3;
        int c = (L & 7) ^ (row & 7);
        Aoff[it] = (size_t)(m0 + row) * K + c * 8;
        Boff[it] = (size_t)(n0 + row) * K + c * 8;
        ldsOff[it] = L * 8;                // ushort elements
    }

    int rowA[4], rowB[2];
#pragma unroll
    for (int i = 0; i < 4; ++i) rowA[i] = wm * 64 + i * 16 + lr;
#pragma unroll
    for (int j = 0; j < 2; ++j) rowB[j] = wn * 32 + j * 16 + lr;

    f32x4 acc[4][2];
#pragma unroll
    for (int i = 0; i < 4; ++i)
#pragma unroll
        for (int j = 0; j < 2; ++j) acc[i][j] = (f32x4)(0.f);

    auto stage = [&](int kb, int buf) {
#pragma unroll
        for (int it = 0; it < 2; ++it) {
            __builtin_amdgcn_global_load_lds(
                (const __attribute__((address_space(1))) void*)(A + Aoff[it] + kb),
                (__attribute__((address_space(3))) void*)(&As[buf][ldsOff[it]]), 16, 0, 0);
            __builtin_amdgcn_global_load_lds(
                (const __attribute__((address_space(1))) void*)(Bt + Boff[it] + kb),
                (__attribute__((address_space(3))) void*)(&Bs[buf][ldsOff[it]]), 16, 0, 0);
        }
    };
    auto compute = [&](int buf) {
#pragma unroll
        for (int ks = 0; ks < 2; ++ks) {
            bf16x8 af[4], bfr[2];
#pragma unroll
            for (int i = 0; i < 4; ++i) {
                int cA = (ks * 4 + q) ^ (rowA[i] & 7);
                af[i] = *(const bf16x8*)(&As[buf][rowA[i] * 64 + cA * 8]);
            }
#pragma unroll
            for (int j = 0; j < 2; ++j) {
                int cB = (ks * 4 + q) ^ (rowB[j] & 7);
                bfr[j] = *(const bf16x8*)(&Bs[buf][rowB[j] * 64 + cB * 8]);
            }
#pragma unroll
            for (int i = 0; i < 4; ++i)
#pragma unroll
                for (int j = 0; j < 2; ++j)
                    acc[i][j] = __builtin_amdgcn_mfma_f32_16x16x32_bf16(
                        af[i], bfr[j], acc[i][j], 0, 0, 0);
        }
    };

    const int nk = K >> 6;
    stage(0, 0);
    __syncthreads();
    int cur = 0;
    for (int t = 0; t < nk; ++t) {
        if (t + 1 < nk) stage((t + 1) << 6, cur ^ 1);
        compute(cur);
        __syncthreads();
        cur ^= 1;
    }

    // epilogue: C/D map col=lane&15, row=(lane>>4)*4+reg
    int colb = n0 + wn * 32 + lr;
    int rowb = m0 + wm * 64 + q * 4;
#pragma unroll
    for (int j = 0; j < 2; ++j) {
        int col = colb + j * 16;
        float bz = bias[col];
#pragma unroll
        for (int i = 0; i < 4; ++i) {
            int row = rowb + i * 16;
#pragma unroll
            for (int r = 0; r < 4; ++r) {
                float v = acc[i][j][r] + bz;
                if (ACT_GELU) v = gelu_fast(v);
                if (!FFN2 || e < NEXP)
                    Cb[(size_t)(row + r) * N + col] = f2b(v);
                else
                    Cf[(size_t)(row + r - SLOT_MAX) * N + col] = v;
            }
        }
    }
}

// ------------------------------- combine -----------------------------------
__global__ void combine_kernel(float* __restrict__ out, const ushort_t* __restrict__ OutS,
                               const int* __restrict__ slot_of, const float* __restrict__ tw) {
    int t = blockIdx.x;
    int d = threadIdx.x * 4;
    int s0 = slot_of[2 * t], s1 = slot_of[2 * t + 1];
    float w0 = tw[2 * t], w1 = tw[2 * t + 1];
    float* po = out + (size_t)t * DDIM + d;
    float4 o = *(float4*)po;
    const ushort_t* p0 = OutS + (size_t)s0 * DDIM + d;
    const ushort_t* p1 = OutS + (size_t)s1 * DDIM + d;
    o.x += w0 * b2f(p0[0]) + w1 * b2f(p1[0]);
    o.y += w0 * b2f(p0[1]) + w1 * b2f(p1[1]);
    o.z += w0 * b2f(p0[2]) + w1 * b2f(p1[2]);
    o.w += w0 * b2f(p0[3]) + w1 * b2f(p1[3]);
    *(float4*)po = o;
}

// ------------------------------- launch ------------------------------------
extern "C" void kernel_launch(void* const* d_in, const int* in_sizes, int n_in,
                              void* d_out, int out_size, void* d_ws, size_t ws_size,
                              hipStream_t stream) {
    const float* x      = (const float*)d_in[0];
    const float* gw     = (const float*)d_in[1];
    const float* w_in   = (const float*)d_in[2];
    const float* b_in   = (const float*)d_in[3];
    const float* w_out  = (const float*)d_in[4];
    const float* b_out  = (const float*)d_in[5];
    const float* sw_in  = (const float*)d_in[6];
    const float* sb_in  = (const float*)d_in[7];
    const float* sw_out = (const float*)d_in[8];
    const float* sb_out = (const float*)d_in[9];
    float* out = (float*)d_out;

    char* ws = (char*)d_ws;
    int*      cnt     = (int*)(ws + OFF_CNT);      // [0..7]=cnt, [8..15]=cur
    int*      offs    = (int*)(ws + OFF_OFFS);
    int*      tidx    = (int*)(ws + OFF_TIDX);
    float*    tw      = (float*)(ws + OFF_TW);
    int*      slot_of = (int*)(ws + OFF_SLOT);
    int*      tok_of  = (int*)(ws + OFF_TOK);
    ushort_t* Xall    = (ushort_t*)(ws + OFF_XALL);
    ushort_t* OutS    = (ushort_t*)(ws + OFF_OUTS); // aliases Xall (used after GEMM1)
    ushort_t* Wt      = (ushort_t*)(ws + OFF_WT);   // [9][N][K], FFN1 then FFN2
    ushort_t* Hbuf    = (ushort_t*)(ws + OFF_H);    // bf16 [13312][4096]

    // routing
    init_kernel<<<(SLOT_MAX + 255) / 256, 256, 0, stream>>>(cnt, tok_of);
    gate_kernel<<<T_TOK, 64, 0, stream>>>(x, gw, tidx, tw, cnt);
    offs_kernel<<<1, 64, 0, stream>>>(cnt, offs);
    assign_kernel<<<(2 * T_TOK + 255) / 256, 256, 0, stream>>>(tidx, offs, cnt + 8,
                                                               slot_of, tok_of);
    build_x<<<M_ALL, 256, 0, stream>>>(x, tok_of, offs, Xall);

    // FFN1 weights: [9][4096][1024] bf16  (w_in experts + sw_in as expert 8)
    transpose_cvt<<<dim3(DDIM / 64, HDIM / 64, NEXP), 256, 0, stream>>>(w_in, Wt, DDIM, HDIM);
    transpose_cvt<<<dim3(DDIM / 64, HDIM / 64, 1), 256, 0, stream>>>(
        sw_in, Wt + (size_t)NEXP * HDIM * DDIM, DDIM, HDIM);
    // H = gelu(Xall @ W1 + b1)
    gemm_moe<true, false><<<dim3(M_ALL / 128, HDIM / 128), 512, 0, stream>>>(
        Xall, Wt, b_in, sb_in, Hbuf, nullptr, offs, HDIM, DDIM);

    // FFN2 weights: [9][1024][4096] bf16
    transpose_cvt<<<dim3(HDIM / 64, DDIM / 64, NEXP), 256, 0, stream>>>(w_out, Wt, HDIM, DDIM);
    transpose_cvt<<<dim3(HDIM / 64, DDIM / 64, 1), 256, 0, stream>>>(
        sw_out, Wt + (size_t)NEXP * HDIM * DDIM, HDIM, DDIM);
    // expert rows -> OutS (bf16); shared rows -> out (fp32, includes bias)
    gemm_moe<false, true><<<dim3(M_ALL / 128, DDIM / 128), 512, 0, stream>>>(
        Hbuf, Wt, b_out, sb_out, OutS, out, offs, DDIM, HDIM);

    // out += w0*OutS[slot0] + w1*OutS[slot1]
    combine_kernel<<<T_TOK, 256, 0, stream>>>(out, OutS, slot_of, tw);
    (void)in_sizes; (void)n_in; (void)out_size; (void)ws_size;
}

// Round 7
// 600.700 us; speedup vs baseline: 1.5777x; 1.0112x over previous
//
#include <hip/hip_runtime.h>
#include <hip/hip_bf16.h>
#include <math.h>

// ---------------------------------------------------------------------------
// MoE block: y = sum_topk2 w_e * FFN_e(x)  +  FFN_shared(x)
// T=4096, D=1024, H=4096, E=8, K=2.  bf16 MFMA compute.
// R7: R6 GEMM (8 waves/512thr, 2 blocks/CU, XOR-swizzled LDS, XCD patch
// swizzle) with the sync structure replaced by raw s_barrier + counted
// vmcnt(4) (T4): stage(t+1) issued at top of iter t, waited at top of iter
// t+1 -> prefetch distance = full iteration, latency no longer exposed.
// ---------------------------------------------------------------------------

typedef unsigned short ushort_t;
typedef __attribute__((ext_vector_type(8))) __bf16 bf16x8;
typedef __attribute__((ext_vector_type(4))) float f32x4;

#define T_TOK 4096
#define DDIM  1024
#define HDIM  4096
#define NEXP  8
#define SLOT_MAX 9216            // 8192 + 8*128 pad headroom
#define M_ALL (SLOT_MAX + T_TOK) // 13312 rows: experts then shared

// workspace layout (bytes)
#define OFF_CNT   0u             // int[8] cnt + int[8] cur
#define OFF_OFFS  64u            // int[16]
#define OFF_TIDX  256u           // int[8192]
#define OFF_TW    33024u         // float[8192]
#define OFF_SLOT  65792u         // int[8192]
#define OFF_TOK   98560u         // int[9216]
#define OFF_XALL  1048576u                        // bf16 [13312][1024] = 27,262,976
#define OFF_OUTS  OFF_XALL                        // bf16 [9216][1024] (aliases Xall)
#define OFF_WT    (OFF_XALL + 27262976u)          // bf16 [9][N][K] = 75,497,472
#define OFF_H     (OFF_WT + 75497472u)            // bf16 [13312][4096] = 109,051,904

__device__ __forceinline__ ushort_t f2b(float f) {
    __hip_bfloat16 h = __float2bfloat16(f);
    return *reinterpret_cast<ushort_t*>(&h);
}
__device__ __forceinline__ float b2f(ushort_t u) {
    __hip_bfloat16 h;
    *reinterpret_cast<ushort_t*>(&h) = u;
    return __bfloat162float(h);
}
// tanh-form GELU (max |dev| from exact erf-GELU ~3e-3; bf16-safe here)
__device__ __forceinline__ float gelu_fast(float v) {
    float u = 0.7978845608f * v * (1.0f + 0.044715f * v * v);
    float t = 1.0f - 2.0f / (__expf(2.0f * u) + 1.0f);
    return 0.5f * v * (1.0f + t);
}

// -------------------------------- init -------------------------------------
__global__ void init_kernel(int* __restrict__ cnt, int* __restrict__ tok_of) {
    int i = blockIdx.x * 256 + threadIdx.x;
    if (i < 16) cnt[i] = 0;
    if (i < SLOT_MAX) tok_of[i] = -1;
}

// -------------------------------- gate -------------------------------------
__global__ void gate_kernel(const float* __restrict__ x, const float* __restrict__ gw,
                            int* __restrict__ tidx, float* __restrict__ tw,
                            int* __restrict__ cnt) {
    int t = blockIdx.x;
    int l = threadIdx.x;
    float acc[NEXP];
#pragma unroll
    for (int e = 0; e < NEXP; ++e) acc[e] = 0.f;
    for (int i = 0; i < DDIM / 64; ++i) {
        float xi = x[(size_t)t * DDIM + i * 64 + l];
#pragma unroll
        for (int e = 0; e < NEXP; ++e)
            acc[e] += xi * gw[e * DDIM + i * 64 + l];
    }
#pragma unroll
    for (int e = 0; e < NEXP; ++e)
        for (int off = 32; off; off >>= 1) acc[e] += __shfl_xor(acc[e], off);
    if (l == 0) {
        float m = acc[0];
#pragma unroll
        for (int e = 1; e < NEXP; ++e) m = fmaxf(m, acc[e]);
        float ex[NEXP], Z = 0.f;
#pragma unroll
        for (int e = 0; e < NEXP; ++e) { ex[e] = __expf(acc[e] - m); Z += ex[e]; }
        int b0 = 0;
#pragma unroll
        for (int e = 1; e < NEXP; ++e) if (ex[e] > ex[b0]) b0 = e;
        int b1 = (b0 == 0) ? 1 : 0;
#pragma unroll
        for (int e = 0; e < NEXP; ++e) if (e != b0 && ex[e] > ex[b1]) b1 = e;
        float inv = 1.0f / Z;
        tidx[2 * t] = b0; tidx[2 * t + 1] = b1;
        tw[2 * t] = ex[b0] * inv; tw[2 * t + 1] = ex[b1] * inv;
        atomicAdd(&cnt[b0], 1);
        atomicAdd(&cnt[b1], 1);
    }
}

// ------------------------------ offsets ------------------------------------
__global__ void offs_kernel(const int* __restrict__ cnt, int* __restrict__ offs) {
    if (threadIdx.x == 0 && blockIdx.x == 0) {
        int o = 0;
#pragma unroll
        for (int e = 0; e < NEXP; ++e) {
            offs[e] = o;
            o += (cnt[e] + 127) & ~127;
        }
        offs[NEXP] = o;
    }
}

// ------------------------------- assign ------------------------------------
// slot order within an expert is atomic-race-dependent, but the OUTPUT is
// permutation-invariant (each slot row computed independently).
__global__ void assign_kernel(const int* __restrict__ tidx, const int* __restrict__ offs,
                              int* __restrict__ cur, int* __restrict__ slot_of,
                              int* __restrict__ tok_of) {
    int i = blockIdx.x * 256 + threadIdx.x;
    if (i >= 2 * T_TOK) return;
    int e = tidx[i];
    int s = offs[e] + atomicAdd(&cur[e], 1);
    slot_of[i] = s;
    tok_of[s] = i >> 1;
}

// ------------------------------- build X -----------------------------------
__global__ void build_x(const float* __restrict__ x, const int* __restrict__ tok_of,
                        const int* __restrict__ offs, ushort_t* __restrict__ Xall) {
    int b = blockIdx.x;
    int k = threadIdx.x * 4;
    int t;
    if (b < SLOT_MAX) {
        if (b >= offs[NEXP]) return;
        t = tok_of[b];
    } else {
        t = b - SLOT_MAX;
    }
    float4 v = make_float4(0.f, 0.f, 0.f, 0.f);
    if (t >= 0) v = *(const float4*)(x + (size_t)t * DDIM + k);
    ushort_t* p = Xall + (size_t)b * DDIM + k;
    p[0] = f2b(v.x); p[1] = f2b(v.y); p[2] = f2b(v.z); p[3] = f2b(v.w);
}

// --------------------------- transpose + cvt -------------------------------
// in [K][N] fp32 -> out [N][K] bf16 ; grid (K/64, N/64, batch)
__global__ void transpose_cvt(const float* __restrict__ in, ushort_t* __restrict__ out,
                              int K, int N) {
    __shared__ float t[64][65];
    size_t zoff = (size_t)blockIdx.z * K * N;
    in += zoff; out += zoff;
    int k0 = blockIdx.x * 64, n0 = blockIdx.y * 64;
    int c = threadIdx.x & 63, r4 = threadIdx.x >> 6;
#pragma unroll
    for (int i = 0; i < 16; ++i) {
        int r = r4 + i * 4;
        t[r][c] = in[(size_t)(k0 + r) * N + n0 + c];
    }
    __syncthreads();
#pragma unroll
    for (int i = 0; i < 16; ++i) {
        int r = r4 + i * 4;
        out[(size_t)(n0 + r) * K + k0 + c] = f2b(t[c][r]);
    }
}

// ------------------------------ GEMM (bt) ----------------------------------
// C[M,N] = act(A[M,K] @ Bt[e][N,K]^T + bias), rows grouped by expert
// (128-aligned), expert 8 = shared. 128x128 tile, BK=64, 8 waves (512 thr,
// wave-tile 64x32), mfma 16x16x32 bf16, XOR-swizzled LDS, per-XCD patch
// swizzle. R7 sync: raw s_barrier + counted vmcnt(4):
//   iter t: stage(t+1,buf^1) [4 loads/thread]; vmcnt(4) -> tile t's loads
//   done, t+1's in flight; s_barrier; compute(buf); s_barrier.
// Prefetch distance = one full iteration; no vmcnt(0) in the main loop.
template <bool ACT_GELU, bool FFN2>
__global__ __launch_bounds__(512, 4) void gemm_moe(
    const ushort_t* __restrict__ A, const ushort_t* __restrict__ WtBase,
    const float* __restrict__ bExp, const float* __restrict__ bSh,
    ushort_t* __restrict__ Cb, float* __restrict__ Cf,
    const int* __restrict__ offs, int N, int K) {
    // ---- per-XCD patch swizzle (bijective; NM%4==0, NN%2==0) ----
    int NMt = gridDim.x, NNt = gridDim.y;
    int flat = blockIdx.y * NMt + blockIdx.x;
    int xcd = flat & 7, rank = flat >> 3;
    int PM = NMt >> 2;                    // patch rows
    int PN = NNt >> 1;                    // patch cols
    int pm = xcd >> 1, pn = xcd & 1;      // 4 x 2 patch grid
    int mi = pm * PM + rank / PN;
    int ni = pn * PN + rank % PN;
    int m0 = mi * 128, n0 = ni * 128;

    int e;
    if (m0 >= SLOT_MAX) {
        e = NEXP;                        // shared region
    } else {
        if (m0 >= offs[NEXP]) return;    // dead pad zone (before any barrier)
        e = 0;
        while (offs[e + 1] <= m0) e++;
    }
    const ushort_t* Bt = WtBase + (size_t)e * N * K;
    const float* bias = (e == NEXP) ? bSh : bExp + (size_t)e * N;

    __shared__ ushort_t As[2][128 * 64];
    __shared__ ushort_t Bs[2][128 * 64];

    int tid = threadIdx.x;
    int lane = tid & 63, wid = tid >> 6;   // 8 waves
    int wm = wid >> 2, wn = wid & 3;       // 2 x 4 wave grid
    int q = lane >> 4, lr = lane & 15;

    // staging: chunk L = it*512 + tid ; row = L>>3, stored chunk = L&7,
    // source chunk = stored ^ (row&7)  (rule #21: pre-swizzled source)
    size_t Aoff[2], Boff[2];
    int ldsOff[2];
#pragma unroll
    for (int it = 0; it < 2; ++it) {
        int L = it * 512 + tid;
        int row = L >> 3;
        int c = (L & 7) ^ (row & 7);
        Aoff[it] = (size_t)(m0 + row) * K + c * 8;
        Boff[it] = (size_t)(n0 + row) * K + c * 8;
        ldsOff[it] = L * 8;                // ushort elements
    }

    int rowA[4], rowB[2];
#pragma unroll
    for (int i = 0; i < 4; ++i) rowA[i] = wm * 64 + i * 16 + lr;
#pragma unroll
    for (int j = 0; j < 2; ++j) rowB[j] = wn * 32 + j * 16 + lr;

    f32x4 acc[4][2];
#pragma unroll
    for (int i = 0; i < 4; ++i)
#pragma unroll
        for (int j = 0; j < 2; ++j) acc[i][j] = (f32x4)(0.f);

    auto stage = [&](int kb, int buf) {    // 4 loads per thread
#pragma unroll
        for (int it = 0; it < 2; ++it) {
            __builtin_amdgcn_global_load_lds(
                (const __attribute__((address_space(1))) void*)(A + Aoff[it] + kb),
                (__attribute__((address_space(3))) void*)(&As[buf][ldsOff[it]]), 16, 0, 0);
            __builtin_amdgcn_global_load_lds(
                (const __attribute__((address_space(1))) void*)(Bt + Boff[it] + kb),
                (__attribute__((address_space(3))) void*)(&Bs[buf][ldsOff[it]]), 16, 0, 0);
        }
    };
    auto compute = [&](int buf) {
#pragma unroll
        for (int ks = 0; ks < 2; ++ks) {
            bf16x8 af[4], bfr[2];
#pragma unroll
            for (int i = 0; i < 4; ++i) {
                int cA = (ks * 4 + q) ^ (rowA[i] & 7);
                af[i] = *(const bf16x8*)(&As[buf][rowA[i] * 64 + cA * 8]);
            }
#pragma unroll
            for (int j = 0; j < 2; ++j) {
                int cB = (ks * 4 + q) ^ (rowB[j] & 7);
                bfr[j] = *(const bf16x8*)(&Bs[buf][rowB[j] * 64 + cB * 8]);
            }
#pragma unroll
            for (int i = 0; i < 4; ++i)
#pragma unroll
                for (int j = 0; j < 2; ++j)
                    acc[i][j] = __builtin_amdgcn_mfma_f32_16x16x32_bf16(
                        af[i], bfr[j], acc[i][j], 0, 0, 0);
        }
    };

    const int nk = K >> 6;
    stage(0, 0);                           // 4 outstanding
    int cur = 0;
    for (int t = 0; t < nk; ++t) {
        if (t + 1 < nk) {
            stage((t + 1) << 6, cur ^ 1);  // 8 outstanding
            asm volatile("s_waitcnt vmcnt(4)" ::: "memory");  // tile t landed
        } else {
            asm volatile("s_waitcnt vmcnt(0)" ::: "memory");
        }
        __builtin_amdgcn_s_barrier();      // all waves see tile t in LDS
        compute(cur);                      // compiler inserts lgkmcnt waits
        __builtin_amdgcn_s_barrier();      // done reading buf before overwrite
        cur ^= 1;
    }

    // epilogue: C/D map col=lane&15, row=(lane>>4)*4+reg
    int colb = n0 + wn * 32 + lr;
    int rowb = m0 + wm * 64 + q * 4;
#pragma unroll
    for (int j = 0; j < 2; ++j) {
        int col = colb + j * 16;
        float bz = bias[col];
#pragma unroll
        for (int i = 0; i < 4; ++i) {
            int row = rowb + i * 16;
#pragma unroll
            for (int r = 0; r < 4; ++r) {
                float v = acc[i][j][r] + bz;
                if (ACT_GELU) v = gelu_fast(v);
                if (!FFN2 || e < NEXP)
                    Cb[(size_t)(row + r) * N + col] = f2b(v);
                else
                    Cf[(size_t)(row + r - SLOT_MAX) * N + col] = v;
            }
        }
    }
}

// ------------------------------- combine -----------------------------------
__global__ void combine_kernel(float* __restrict__ out, const ushort_t* __restrict__ OutS,
                               const int* __restrict__ slot_of, const float* __restrict__ tw) {
    int t = blockIdx.x;
    int d = threadIdx.x * 4;
    int s0 = slot_of[2 * t], s1 = slot_of[2 * t + 1];
    float w0 = tw[2 * t], w1 = tw[2 * t + 1];
    float* po = out + (size_t)t * DDIM + d;
    float4 o = *(float4*)po;
    const ushort_t* p0 = OutS + (size_t)s0 * DDIM + d;
    const ushort_t* p1 = OutS + (size_t)s1 * DDIM + d;
    o.x += w0 * b2f(p0[0]) + w1 * b2f(p1[0]);
    o.y += w0 * b2f(p0[1]) + w1 * b2f(p1[1]);
    o.z += w0 * b2f(p0[2]) + w1 * b2f(p1[2]);
    o.w += w0 * b2f(p0[3]) + w1 * b2f(p1[3]);
    *(float4*)po = o;
}

// ------------------------------- launch ------------------------------------
extern "C" void kernel_launch(void* const* d_in, const int* in_sizes, int n_in,
                              void* d_out, int out_size, void* d_ws, size_t ws_size,
                              hipStream_t stream) {
    const float* x      = (const float*)d_in[0];
    const float* gw     = (const float*)d_in[1];
    const float* w_in   = (const float*)d_in[2];
    const float* b_in   = (const float*)d_in[3];
    const float* w_out  = (const float*)d_in[4];
    const float* b_out  = (const float*)d_in[5];
    const float* sw_in  = (const float*)d_in[6];
    const float* sb_in  = (const float*)d_in[7];
    const float* sw_out = (const float*)d_in[8];
    const float* sb_out = (const float*)d_in[9];
    float* out = (float*)d_out;

    char* ws = (char*)d_ws;
    int*      cnt     = (int*)(ws + OFF_CNT);      // [0..7]=cnt, [8..15]=cur
    int*      offs    = (int*)(ws + OFF_OFFS);
    int*      tidx    = (int*)(ws + OFF_TIDX);
    float*    tw      = (float*)(ws + OFF_TW);
    int*      slot_of = (int*)(ws + OFF_SLOT);
    int*      tok_of  = (int*)(ws + OFF_TOK);
    ushort_t* Xall    = (ushort_t*)(ws + OFF_XALL);
    ushort_t* OutS    = (ushort_t*)(ws + OFF_OUTS); // aliases Xall (used after GEMM1)
    ushort_t* Wt      = (ushort_t*)(ws + OFF_WT);   // [9][N][K], FFN1 then FFN2
    ushort_t* Hbuf    = (ushort_t*)(ws + OFF_H);    // bf16 [13312][4096]

    // routing
    init_kernel<<<(SLOT_MAX + 255) / 256, 256, 0, stream>>>(cnt, tok_of);
    gate_kernel<<<T_TOK, 64, 0, stream>>>(x, gw, tidx, tw, cnt);
    offs_kernel<<<1, 64, 0, stream>>>(cnt, offs);
    assign_kernel<<<(2 * T_TOK + 255) / 256, 256, 0, stream>>>(tidx, offs, cnt + 8,
                                                               slot_of, tok_of);
    build_x<<<M_ALL, 256, 0, stream>>>(x, tok_of, offs, Xall);

    // FFN1 weights: [9][4096][1024] bf16  (w_in experts + sw_in as expert 8)
    transpose_cvt<<<dim3(DDIM / 64, HDIM / 64, NEXP), 256, 0, stream>>>(w_in, Wt, DDIM, HDIM);
    transpose_cvt<<<dim3(DDIM / 64, HDIM / 64, 1), 256, 0, stream>>>(
        sw_in, Wt + (size_t)NEXP * HDIM * DDIM, DDIM, HDIM);
    // H = gelu(Xall @ W1 + b1)
    gemm_moe<true, false><<<dim3(M_ALL / 128, HDIM / 128), 512, 0, stream>>>(
        Xall, Wt, b_in, sb_in, Hbuf, nullptr, offs, HDIM, DDIM);

    // FFN2 weights: [9][1024][4096] bf16
    transpose_cvt<<<dim3(HDIM / 64, DDIM / 64, NEXP), 256, 0, stream>>>(w_out, Wt, HDIM, DDIM);
    transpose_cvt<<<dim3(HDIM / 64, DDIM / 64, 1), 256, 0, stream>>>(
        sw_out, Wt + (size_t)NEXP * HDIM * DDIM, HDIM, DDIM);
    // expert rows -> OutS (bf16); shared rows -> out (fp32, includes bias)
    gemm_moe<false, true><<<dim3(M_ALL / 128, DDIM / 128), 512, 0, stream>>>(
        Hbuf, Wt, b_out, sb_out, OutS, out, offs, DDIM, HDIM);

    // out += w0*OutS[slot0] + w1*OutS[slot1]
    combine_kernel<<<T_TOK, 256, 0, stream>>>(out, OutS, slot_of, tw);
    (void)in_sizes; (void)n_in; (void)out_size; (void)ws_size;
}

// Round 8
// 573.543 us; speedup vs baseline: 1.6524x; 1.0473x over previous
//
#include <hip/hip_runtime.h>
#include <hip/hip_bf16.h>
#include <math.h>

// ---------------------------------------------------------------------------
// MoE block: y = sum_topk2 w_e * FFN_e(x)  +  FFN_shared(x)
// T=4096, D=1024, H=4096, E=8, K=2.  bf16 MFMA compute.
// R8: 256x256 block, 1024 threads (16 waves, 4x4), wave-tile 64x64 ->
// LDS-read amplification 3x->2x AND 4 waves/SIMD TLP. R7 sync skeleton
// (stage(t+1), counted vmcnt(4), raw s_barrier pair). 128KB LDS dbuf.
// ---------------------------------------------------------------------------

typedef unsigned short ushort_t;
typedef __attribute__((ext_vector_type(8))) __bf16 bf16x8;
typedef __attribute__((ext_vector_type(4))) float f32x4;

#define T_TOK 4096
#define DDIM  1024
#define HDIM  4096
#define NEXP  8
#define SLOT_PAD 10240           // 8192 + 8*256 pad headroom (256-aligned regions)
#define M_ALL (SLOT_PAD + T_TOK) // 14336 rows: experts then shared

// workspace layout (bytes)
#define OFF_CNT   0u             // int[8] cnt + int[8] cur
#define OFF_OFFS  64u            // int[16]
#define OFF_TIDX  256u           // int[8192]
#define OFF_TW    33024u         // float[8192]
#define OFF_SLOT  65792u         // int[8192]
#define OFF_TOK   98560u         // int[10240]
#define OFF_XALL  1048576u                        // bf16 [14336][1024] = 29,360,128
#define OFF_OUTS  OFF_XALL                        // bf16 [10240][1024] (aliases Xall)
#define OFF_WT    (OFF_XALL + 29360128u)          // bf16 [9][N][K] = 75,497,472
#define OFF_H     (OFF_WT + 75497472u)            // bf16 [14336][4096] = 117,440,512

__device__ __forceinline__ ushort_t f2b(float f) {
    __hip_bfloat16 h = __float2bfloat16(f);
    return *reinterpret_cast<ushort_t*>(&h);
}
__device__ __forceinline__ float b2f(ushort_t u) {
    __hip_bfloat16 h;
    *reinterpret_cast<ushort_t*>(&h) = u;
    return __bfloat162float(h);
}
// tanh-form GELU (max |dev| from exact erf-GELU ~3e-3; bf16-safe here)
__device__ __forceinline__ float gelu_fast(float v) {
    float u = 0.7978845608f * v * (1.0f + 0.044715f * v * v);
    float t = 1.0f - 2.0f / (__expf(2.0f * u) + 1.0f);
    return 0.5f * v * (1.0f + t);
}

// -------------------------------- init -------------------------------------
__global__ void init_kernel(int* __restrict__ cnt, int* __restrict__ tok_of) {
    int i = blockIdx.x * 256 + threadIdx.x;
    if (i < 16) cnt[i] = 0;
    if (i < SLOT_PAD) tok_of[i] = -1;
}

// -------------------------------- gate -------------------------------------
__global__ void gate_kernel(const float* __restrict__ x, const float* __restrict__ gw,
                            int* __restrict__ tidx, float* __restrict__ tw,
                            int* __restrict__ cnt) {
    int t = blockIdx.x;
    int l = threadIdx.x;
    float acc[NEXP];
#pragma unroll
    for (int e = 0; e < NEXP; ++e) acc[e] = 0.f;
    for (int i = 0; i < DDIM / 64; ++i) {
        float xi = x[(size_t)t * DDIM + i * 64 + l];
#pragma unroll
        for (int e = 0; e < NEXP; ++e)
            acc[e] += xi * gw[e * DDIM + i * 64 + l];
    }
#pragma unroll
    for (int e = 0; e < NEXP; ++e)
        for (int off = 32; off; off >>= 1) acc[e] += __shfl_xor(acc[e], off);
    if (l == 0) {
        float m = acc[0];
#pragma unroll
        for (int e = 1; e < NEXP; ++e) m = fmaxf(m, acc[e]);
        float ex[NEXP], Z = 0.f;
#pragma unroll
        for (int e = 0; e < NEXP; ++e) { ex[e] = __expf(acc[e] - m); Z += ex[e]; }
        int b0 = 0;
#pragma unroll
        for (int e = 1; e < NEXP; ++e) if (ex[e] > ex[b0]) b0 = e;
        int b1 = (b0 == 0) ? 1 : 0;
#pragma unroll
        for (int e = 0; e < NEXP; ++e) if (e != b0 && ex[e] > ex[b1]) b1 = e;
        float inv = 1.0f / Z;
        tidx[2 * t] = b0; tidx[2 * t + 1] = b1;
        tw[2 * t] = ex[b0] * inv; tw[2 * t + 1] = ex[b1] * inv;
        atomicAdd(&cnt[b0], 1);
        atomicAdd(&cnt[b1], 1);
    }
}

// ------------------------------ offsets ------------------------------------
__global__ void offs_kernel(const int* __restrict__ cnt, int* __restrict__ offs) {
    if (threadIdx.x == 0 && blockIdx.x == 0) {
        int o = 0;
#pragma unroll
        for (int e = 0; e < NEXP; ++e) {
            offs[e] = o;
            o += (cnt[e] + 255) & ~255;
        }
        offs[NEXP] = o;
    }
}

// ------------------------------- assign ------------------------------------
// slot order within an expert is atomic-race-dependent, but the OUTPUT is
// permutation-invariant (each slot row computed independently).
__global__ void assign_kernel(const int* __restrict__ tidx, const int* __restrict__ offs,
                              int* __restrict__ cur, int* __restrict__ slot_of,
                              int* __restrict__ tok_of) {
    int i = blockIdx.x * 256 + threadIdx.x;
    if (i >= 2 * T_TOK) return;
    int e = tidx[i];
    int s = offs[e] + atomicAdd(&cur[e], 1);
    slot_of[i] = s;
    tok_of[s] = i >> 1;
}

// ------------------------------- build X -----------------------------------
__global__ void build_x(const float* __restrict__ x, const int* __restrict__ tok_of,
                        const int* __restrict__ offs, ushort_t* __restrict__ Xall) {
    int b = blockIdx.x;
    int k = threadIdx.x * 4;
    int t;
    if (b < SLOT_PAD) {
        if (b >= offs[NEXP]) return;
        t = tok_of[b];
    } else {
        t = b - SLOT_PAD;
    }
    float4 v = make_float4(0.f, 0.f, 0.f, 0.f);
    if (t >= 0) v = *(const float4*)(x + (size_t)t * DDIM + k);
    ushort_t* p = Xall + (size_t)b * DDIM + k;
    p[0] = f2b(v.x); p[1] = f2b(v.y); p[2] = f2b(v.z); p[3] = f2b(v.w);
}

// --------------------------- transpose + cvt -------------------------------
// in [K][N] fp32 -> out [N][K] bf16 ; grid (K/64, N/64, batch)
__global__ void transpose_cvt(const float* __restrict__ in, ushort_t* __restrict__ out,
                              int K, int N) {
    __shared__ float t[64][65];
    size_t zoff = (size_t)blockIdx.z * K * N;
    in += zoff; out += zoff;
    int k0 = blockIdx.x * 64, n0 = blockIdx.y * 64;
    int c = threadIdx.x & 63, r4 = threadIdx.x >> 6;
#pragma unroll
    for (int i = 0; i < 16; ++i) {
        int r = r4 + i * 4;
        t[r][c] = in[(size_t)(k0 + r) * N + n0 + c];
    }
    __syncthreads();
#pragma unroll
    for (int i = 0; i < 16; ++i) {
        int r = r4 + i * 4;
        out[(size_t)(n0 + r) * K + k0 + c] = f2b(t[c][r]);
    }
}

// ------------------------------ GEMM (bt) ----------------------------------
// C[M,N] = act(A[M,K] @ Bt[e][N,K]^T + bias), rows grouped by expert
// (256-aligned), expert 8 = shared. 256x256 block, BK=64, 16 waves (1024
// thr, 4x4 wave grid, wave-tile 64x64), mfma 16x16x32 bf16, XOR-swizzled
// LDS (pre-swizzled source, rule #21), per-XCD patch swizzle.
// Sync (R7-proven): iter t: stage(t+1,buf^1)[4 loads/thr]; vmcnt(4);
// s_barrier; compute(buf); s_barrier. No vmcnt(0) in main loop.
template <bool ACT_GELU, bool FFN2>
__global__ __launch_bounds__(1024, 4) void gemm_moe(
    const ushort_t* __restrict__ A, const ushort_t* __restrict__ WtBase,
    const float* __restrict__ bExp, const float* __restrict__ bSh,
    ushort_t* __restrict__ Cb, float* __restrict__ Cf,
    const int* __restrict__ offs, int N, int K) {
    // ---- per-XCD patch swizzle (bijective; NM%4==0, NN%2==0) ----
    int NMt = gridDim.x, NNt = gridDim.y;
    int flat = blockIdx.y * NMt + blockIdx.x;
    int xcd = flat & 7, rank = flat >> 3;
    int PM = NMt >> 2;                    // patch rows (14)
    int PN = NNt >> 1;                    // patch cols (8 or 2)
    int pm = xcd >> 1, pn = xcd & 1;      // 4 x 2 patch grid
    int mi = pm * PM + rank / PN;
    int ni = pn * PN + rank % PN;
    int m0 = mi * 256, n0 = ni * 256;

    int e;
    if (m0 >= SLOT_PAD) {
        e = NEXP;                        // shared region
    } else {
        if (m0 >= offs[NEXP]) return;    // dead pad zone (before any barrier)
        e = 0;
        while (offs[e + 1] <= m0) e++;
    }
    const ushort_t* Bt = WtBase + (size_t)e * N * K;
    const float* bias = (e == NEXP) ? bSh : bExp + (size_t)e * N;

    __shared__ ushort_t As[2][256 * 64];   // 64 KB
    __shared__ ushort_t Bs[2][256 * 64];   // 64 KB

    int tid = threadIdx.x;
    int lane = tid & 63, wid = tid >> 6;   // 16 waves
    int wm = wid >> 2, wn = wid & 3;       // 4 x 4 wave grid
    int q = lane >> 4, lr = lane & 15;

    // staging: per operand 2048 16B-chunks; thread does L = it*1024 + tid.
    // row = L>>3, stored chunk = L&7, source chunk = stored ^ (row&7).
    size_t Aoff[2], Boff[2];
    int ldsOff[2];
#pragma unroll
    for (int it = 0; it < 2; ++it) {
        int L = it * 1024 + tid;
        int row = L >> 3;
        int c = (L & 7) ^ (row & 7);
        Aoff[it] = (size_t)(m0 + row) * K + c * 8;
        Boff[it] = (size_t)(n0 + row) * K + c * 8;
        ldsOff[it] = L * 8;                // ushort elements
    }

    int rowA[4], rowB[4];
#pragma unroll
    for (int i = 0; i < 4; ++i) rowA[i] = wm * 64 + i * 16 + lr;
#pragma unroll
    for (int j = 0; j < 4; ++j) rowB[j] = wn * 64 + j * 16 + lr;

    f32x4 acc[4][4];
#pragma unroll
    for (int i = 0; i < 4; ++i)
#pragma unroll
        for (int j = 0; j < 4; ++j) acc[i][j] = (f32x4)(0.f);

    auto stage = [&](int kb, int buf) {    // 4 loads per thread
#pragma unroll
        for (int it = 0; it < 2; ++it) {
            __builtin_amdgcn_global_load_lds(
                (const __attribute__((address_space(1))) void*)(A + Aoff[it] + kb),
                (__attribute__((address_space(3))) void*)(&As[buf][ldsOff[it]]), 16, 0, 0);
            __builtin_amdgcn_global_load_lds(
                (const __attribute__((address_space(1))) void*)(Bt + Boff[it] + kb),
                (__attribute__((address_space(3))) void*)(&Bs[buf][ldsOff[it]]), 16, 0, 0);
        }
    };
    auto compute = [&](int buf) {
#pragma unroll
        for (int ks = 0; ks < 2; ++ks) {
            bf16x8 af[4], bfr[4];
#pragma unroll
            for (int i = 0; i < 4; ++i) {
                int cA = (ks * 4 + q) ^ (rowA[i] & 7);
                af[i] = *(const bf16x8*)(&As[buf][rowA[i] * 64 + cA * 8]);
            }
#pragma unroll
            for (int j = 0; j < 4; ++j) {
                int cB = (ks * 4 + q) ^ (rowB[j] & 7);
                bfr[j] = *(const bf16x8*)(&Bs[buf][rowB[j] * 64 + cB * 8]);
            }
#pragma unroll
            for (int i = 0; i < 4; ++i)
#pragma unroll
                for (int j = 0; j < 4; ++j)
                    acc[i][j] = __builtin_amdgcn_mfma_f32_16x16x32_bf16(
                        af[i], bfr[j], acc[i][j], 0, 0, 0);
        }
    };

    const int nk = K >> 6;
    stage(0, 0);                           // 4 outstanding
    int cur = 0;
    for (int t = 0; t < nk; ++t) {
        if (t + 1 < nk) {
            stage((t + 1) << 6, cur ^ 1);  // 8 outstanding
            asm volatile("s_waitcnt vmcnt(4)" ::: "memory");  // tile t landed
        } else {
            asm volatile("s_waitcnt vmcnt(0)" ::: "memory");
        }
        __builtin_amdgcn_s_barrier();      // all waves see tile t in LDS
        compute(cur);                      // compiler inserts lgkmcnt waits
        __builtin_amdgcn_s_barrier();      // done reading buf before overwrite
        cur ^= 1;
    }

    // epilogue: C/D map col=lane&15, row=(lane>>4)*4+reg
    int colb = n0 + wn * 64 + lr;
    int rowb = m0 + wm * 64 + q * 4;
#pragma unroll
    for (int j = 0; j < 4; ++j) {
        int col = colb + j * 16;
        float bz = bias[col];
#pragma unroll
        for (int i = 0; i < 4; ++i) {
            int row = rowb + i * 16;
#pragma unroll
            for (int r = 0; r < 4; ++r) {
                float v = acc[i][j][r] + bz;
                if (ACT_GELU) v = gelu_fast(v);
                if (!FFN2 || e < NEXP)
                    Cb[(size_t)(row + r) * N + col] = f2b(v);
                else
                    Cf[(size_t)(row + r - SLOT_PAD) * N + col] = v;
            }
        }
    }
}

// ------------------------------- combine -----------------------------------
__global__ void combine_kernel(float* __restrict__ out, const ushort_t* __restrict__ OutS,
                               const int* __restrict__ slot_of, const float* __restrict__ tw) {
    int t = blockIdx.x;
    int d = threadIdx.x * 4;
    int s0 = slot_of[2 * t], s1 = slot_of[2 * t + 1];
    float w0 = tw[2 * t], w1 = tw[2 * t + 1];
    float* po = out + (size_t)t * DDIM + d;
    float4 o = *(float4*)po;
    const ushort_t* p0 = OutS + (size_t)s0 * DDIM + d;
    const ushort_t* p1 = OutS + (size_t)s1 * DDIM + d;
    o.x += w0 * b2f(p0[0]) + w1 * b2f(p1[0]);
    o.y += w0 * b2f(p0[1]) + w1 * b2f(p1[1]);
    o.z += w0 * b2f(p0[2]) + w1 * b2f(p1[2]);
    o.w += w0 * b2f(p0[3]) + w1 * b2f(p1[3]);
    *(float4*)po = o;
}

// ------------------------------- launch ------------------------------------
extern "C" void kernel_launch(void* const* d_in, const int* in_sizes, int n_in,
                              void* d_out, int out_size, void* d_ws, size_t ws_size,
                              hipStream_t stream) {
    const float* x      = (const float*)d_in[0];
    const float* gw     = (const float*)d_in[1];
    const float* w_in   = (const float*)d_in[2];
    const float* b_in   = (const float*)d_in[3];
    const float* w_out  = (const float*)d_in[4];
    const float* b_out  = (const float*)d_in[5];
    const float* sw_in  = (const float*)d_in[6];
    const float* sb_in  = (const float*)d_in[7];
    const float* sw_out = (const float*)d_in[8];
    const float* sb_out = (const float*)d_in[9];
    float* out = (float*)d_out;

    char* ws = (char*)d_ws;
    int*      cnt     = (int*)(ws + OFF_CNT);      // [0..7]=cnt, [8..15]=cur
    int*      offs    = (int*)(ws + OFF_OFFS);
    int*      tidx    = (int*)(ws + OFF_TIDX);
    float*    tw      = (float*)(ws + OFF_TW);
    int*      slot_of = (int*)(ws + OFF_SLOT);
    int*      tok_of  = (int*)(ws + OFF_TOK);
    ushort_t* Xall    = (ushort_t*)(ws + OFF_XALL);
    ushort_t* OutS    = (ushort_t*)(ws + OFF_OUTS); // aliases Xall (used after GEMM1)
    ushort_t* Wt      = (ushort_t*)(ws + OFF_WT);   // [9][N][K], FFN1 then FFN2
    ushort_t* Hbuf    = (ushort_t*)(ws + OFF_H);    // bf16 [14336][4096]

    // routing
    init_kernel<<<(SLOT_PAD + 255) / 256, 256, 0, stream>>>(cnt, tok_of);
    gate_kernel<<<T_TOK, 64, 0, stream>>>(x, gw, tidx, tw, cnt);
    offs_kernel<<<1, 64, 0, stream>>>(cnt, offs);
    assign_kernel<<<(2 * T_TOK + 255) / 256, 256, 0, stream>>>(tidx, offs, cnt + 8,
                                                               slot_of, tok_of);
    build_x<<<M_ALL, 256, 0, stream>>>(x, tok_of, offs, Xall);

    // FFN1 weights: [9][4096][1024] bf16  (w_in experts + sw_in as expert 8)
    transpose_cvt<<<dim3(DDIM / 64, HDIM / 64, NEXP), 256, 0, stream>>>(w_in, Wt, DDIM, HDIM);
    transpose_cvt<<<dim3(DDIM / 64, HDIM / 64, 1), 256, 0, stream>>>(
        sw_in, Wt + (size_t)NEXP * HDIM * DDIM, DDIM, HDIM);
    // H = gelu(Xall @ W1 + b1)
    gemm_moe<true, false><<<dim3(M_ALL / 256, HDIM / 256), 1024, 0, stream>>>(
        Xall, Wt, b_in, sb_in, Hbuf, nullptr, offs, HDIM, DDIM);

    // FFN2 weights: [9][1024][4096] bf16
    transpose_cvt<<<dim3(HDIM / 64, DDIM / 64, NEXP), 256, 0, stream>>>(w_out, Wt, HDIM, DDIM);
    transpose_cvt<<<dim3(HDIM / 64, DDIM / 64, 1), 256, 0, stream>>>(
        sw_out, Wt + (size_t)NEXP * HDIM * DDIM, HDIM, DDIM);
    // expert rows -> OutS (bf16); shared rows -> out (fp32, includes bias)
    gemm_moe<false, true><<<dim3(M_ALL / 256, DDIM / 256), 1024, 0, stream>>>(
        Hbuf, Wt, b_out, sb_out, OutS, out, offs, DDIM, HDIM);

    // out += w0*OutS[slot0] + w1*OutS[slot1]
    combine_kernel<<<T_TOK, 256, 0, stream>>>(out, OutS, slot_of, tw);
    (void)in_sizes; (void)n_in; (void)out_size; (void)ws_size;
}